// Round 8
// baseline (280.326 us; speedup 1.0000x reference)
//
#include <hip/hip_runtime.h>

typedef unsigned short u16;
typedef unsigned char u8;
typedef __attribute__((ext_vector_type(2))) float floatx2;
typedef __attribute__((ext_vector_type(4))) float floatx4;
typedef __attribute__((ext_vector_type(8))) __bf16 bf16x8;
typedef __attribute__((ext_vector_type(2))) unsigned short us2;
typedef __attribute__((ext_vector_type(4))) unsigned short us4;
typedef __attribute__((ext_vector_type(8))) unsigned short us8;
typedef __attribute__((ext_vector_type(2))) unsigned int u32x2;

static __device__ __forceinline__ float b2f(u16 v) {
    union { unsigned u; float f; } x; x.u = ((unsigned)v) << 16; return x.f;
}
static __device__ __forceinline__ u16 f2b(float f) {
    union { float f; unsigned u; } x; x.f = f;
    unsigned u = x.u;
    return (u16)((u + 0x7fffu + ((u >> 16) & 1u)) >> 16);
}

#define GLOAD_LDS16(g, l) __builtin_amdgcn_global_load_lds( \
    (const __attribute__((address_space(1))) void*)(g),     \
    (__attribute__((address_space(3))) void*)(l), 16, 0, 0)

#define CAP 64
#define SPILLMAX 4096
#define NBLK 768           // 3 blocks/CU; LDS allows 6 -> co-residency guaranteed
#define NGRP 8
#define GRPSZ (NBLK / NGRP)  // 96

// Per-block dtype self-detection: P(misdetect fp32) ~ 1e-65.
static __device__ __forceinline__ int detect_blk(const u16* __restrict__ p,
                                                 int nelem, int* sh) {
    if (threadIdx.x == 0) *sh = 0;
    __syncthreads();
    const int lim = nelem < 512 ? nelem : 512;
    int found = 0;
    for (int j = threadIdx.x; 2 * j < lim; j += 256) {
        unsigned v = p[2 * j] & 0x7fffu;
        if (v >= 0x4280u) found = 1;  // |bf16(bits)| >= 64.0
    }
    if (found) atomicOr(sh, 1);
    __syncthreads();
    return *sh;
}

// Bijective XCD-chunked swizzle (m204).
static __device__ __forceinline__ int xcd_swz(int L, int nwg) {
    const int q = nwg >> 3, r = nwg & 7;
    const int x = L & 7, i = L >> 3;
    return (x < r ? x * (q + 1) : r * (q + 1) + (x - r) * q) + i;
}

// ---- grid barrier v3: tree arrival + TREE BROADCAST + backoff (R5 post-mortem) --
// R5's v2 fixed RMW-polling but all 767 waiters still polled ONE line:
// 767 pollers / 0.85us = 1 access / 1.1ns >> ~15ns/line service rate -> ~11us
// queue per poll round -> ~40us/barrier. v3: root bumps 8 per-group gen lines;
// each block polls only its group's line (96 pollers / ~1.7us = 18ns apart,
// below service rate -> no queuing). Release chain: arrival ACQ_REL RMWs flush
// each arriver's XCD L2; publisher's RELEASE stores order the gen bumps;
// waiters fence-acquire after observing the bump.
static __device__ __forceinline__ void grid_sync(int* grp_arr, int* root,
                                                 int* grp_gen) {
    __syncthreads();
    if (threadIdx.x == 0) {
        const int g = blockIdx.x & (NGRP - 1);
        int* ga = grp_arr + g * 32;           // 128 B apart
        int* gg = grp_gen + g * 32;
        const int myg = __hip_atomic_load(gg, __ATOMIC_RELAXED,
                                          __HIP_MEMORY_SCOPE_AGENT);
        int published = 0;
        if (__hip_atomic_fetch_add(ga, 1, __ATOMIC_ACQ_REL,
                                   __HIP_MEMORY_SCOPE_AGENT) == GRPSZ - 1) {
            __hip_atomic_store(ga, 0, __ATOMIC_RELAXED,
                               __HIP_MEMORY_SCOPE_AGENT);
            if (__hip_atomic_fetch_add(root, 1, __ATOMIC_ACQ_REL,
                                       __HIP_MEMORY_SCOPE_AGENT) == NGRP - 1) {
                __hip_atomic_store(root, 0, __ATOMIC_RELAXED,
                                   __HIP_MEMORY_SCOPE_AGENT);
#pragma unroll
                for (int k = 0; k < NGRP; ++k)
                    __hip_atomic_store(grp_gen + k * 32, myg + 1,
                                       __ATOMIC_RELEASE,
                                       __HIP_MEMORY_SCOPE_AGENT);
                published = 1;
            }
        }
        if (!published) {
            int it = 0;
            while (__hip_atomic_load(gg, __ATOMIC_RELAXED,
                                     __HIP_MEMORY_SCOPE_AGENT) == myg) {
                if (it < 2) __builtin_amdgcn_s_sleep(8);   // ~0.2us early
                else        __builtin_amdgcn_s_sleep(64);  // ~1.7us steady
                ++it;
            }
        }
        __builtin_amdgcn_fence(__ATOMIC_ACQUIRE, "agent");
    }
    __syncthreads();
}

// ================= phase A body: buckets + all conversions =======================
static __device__ void d1_body(
    int b, const int* __restrict__ src, const int* __restrict__ dst, int E, int Nn,
    int* __restrict__ cnt, int* __restrict__ bucket,
    int* __restrict__ nspill, int* __restrict__ spill,
    const void* __restrict__ h, const void* __restrict__ W1,
    const void* __restrict__ b1, const void* __restrict__ W2,
    const void* __restrict__ b2,
    u16* __restrict__ Hb, u16* __restrict__ W1T, u16* __restrict__ W2T,
    u16* __restrict__ b1c, u16* __restrict__ b2c, int* __restrict__ flags,
    int nFill, int nHb, u16* smem, int* shp) {
    u16 (*tile)[33] = (u16(*)[33])smem;
    const int t = threadIdx.x;

    if (b < nFill) {  // -------- bucket fill --------
        int e = b * 256 + t;
        if (e < E) {
            int d = dst[e], s = src[e];
            if ((unsigned)d < (unsigned)Nn && (unsigned)s < (unsigned)Nn) {
                int p = atomicAdd(&cnt[d], 1);
                if (p < CAP) bucket[d * CAP + p] = s;
                else {
                    int q = atomicAdd(nspill, 1);
                    if (q < SPILLMAX) { spill[2 * q] = d; spill[2 * q + 1] = s; }
                }
            }
        }
    } else if (b < nFill + nHb) {  // -------- Hb cvt --------
        const int f = detect_blk((const u16*)h, Nn * 512, shp);
        int i = ((b - nFill) * 256 + t) * 8;
        if (i < Nn * 512) {
            if (f) {
                const floatx4* s = (const floatx4*)((const float*)h + i);
                floatx4 v0 = s[0], v1 = s[1];
                us8 o;
                o[0] = f2b(v0[0]); o[1] = f2b(v0[1]); o[2] = f2b(v0[2]); o[3] = f2b(v0[3]);
                o[4] = f2b(v1[0]); o[5] = f2b(v1[1]); o[6] = f2b(v1[2]); o[7] = f2b(v1[3]);
                *(us8*)(Hb + i) = o;
            } else {
                *(us8*)(Hb + i) = *(const us8*)((const u16*)h + i);
            }
        }
    } else if (b < nFill + nHb + 512) {  // -------- W1 -> W1T --------
        const int f = detect_blk((const u16*)W1, 1024 * 512, shp);
        int sub = b - nFill - nHb;
        int half = sub >> 8, idx = sub & 255;
        const int bx = (idx & 15) * 32, by = (idx >> 4) * 32;
        const int koff = half * 512, noff = half * 512;
        const int tx = t & 31, ty = t >> 5;
        for (int i = ty; i < 32; i += 8) {
            long id = (long)(koff + by + i) * 512 + (bx + tx);
            tile[i][tx] = f ? f2b(((const float*)W1)[id]) : ((const u16*)W1)[id];
        }
        __syncthreads();
        for (int i = ty; i < 32; i += 8)
            W1T[(long)(noff + bx + i) * 512 + (by + tx)] = tile[tx][i];
    } else if (b < nFill + nHb + 640) {  // -------- W2 -> W2T --------
        const int f = detect_blk((const u16*)W2, 1024 * 128, shp);
        int sub = b - nFill - nHb - 512;
        int half = sub >> 6, idx = sub & 63;
        const int bx = (idx & 3) * 32, by = (idx >> 2) * 32;
        const int koff = half * 512, noff = half * 128;
        const int tx = t & 31, ty = t >> 5;
        for (int i = ty; i < 32; i += 8) {
            long id = (long)(koff + by + i) * 128 + (bx + tx);
            tile[i][tx] = f ? f2b(((const float*)W2)[id]) : ((const u16*)W2)[id];
        }
        __syncthreads();
        for (int i = ty; i < 32; i += 8)
            W2T[(long)(noff + bx + i) * 512 + (by + tx)] = tile[tx][i];
    } else {  // -------- biases + out-dtype flag --------
        const int f1 = detect_blk((const u16*)b1, 512, shp);
        for (int i = t; i < 512; i += 256)
            b1c[i] = f1 ? f2b(((const float*)b1)[i]) : ((const u16*)b1)[i];
        const int f2 = detect_blk((const u16*)b2, 128, shp);
        if (t < 128)
            b2c[t] = f2 ? f2b(((const float*)b2)[t]) : ((const u16*)b2)[t];
        const int fh = detect_blk((const u16*)h, Nn * 512, shp);
        if (t == 0) flags[0] = fh;
    }
}

// ================= 64x128 GEMM core — 2-phase dbuf + XOR bank-swizzle ============
// (R7 core, harness-verified bit-identical.) LDS dest stays linear
// (global_load_lds rule #21); SOURCE chunk address pre-swizzled with
// f(r) = (r&3)^((r>>2)&3); reads apply the same XOR -> 8-way conflict -> 2-way.
__device__ __forceinline__ void gemm_acc64(const u16* __restrict__ A,
                                           const u16* __restrict__ Bt,
                                           long brow, int bobs,
                                           floatx4 acc[4][2], u16* lA, u16* lB) {
    const int tid = threadIdx.x;
    const int wv = tid >> 6;
    const int ln = tid & 63;
    const int lrow = ln >> 2;
    const int lks = (((ln & 3) ^ ((ln >> 2) & 3) ^ ((ln >> 4) & 3))) * 8;
    const int m0 = ln & 15;
    const int kqs = (((ln >> 4) ^ (m0 & 3) ^ ((m0 >> 2) & 3))) * 8;
    const int wc = wv * 32;

#pragma unroll
    for (int i = 0; i < 4; ++i)
#pragma unroll
        for (int j = 0; j < 2; ++j) acc[i][j] = (floatx4){0.f, 0.f, 0.f, 0.f};

    const u16* gA = A + (brow + wv * 16 + lrow) * 512 + lks;

    auto STAGE = [&](int kt, int sel) {
        u16* dA = lA + sel * 2048 + wv * 512;
        u16* dB = lB + sel * 4096;
        GLOAD_LDS16(gA + kt, dA);
#pragma unroll
        for (int ii = 0; ii < 2; ++ii) {
            const int c = ii * 4 + wv;
            GLOAD_LDS16(Bt + (long)(bobs + c * 16 + lrow) * 512 + kt + lks,
                        dB + c * 512);
        }
    };
    auto COMPUTE = [&](int sel) {
        const u16* rA = lA + sel * 2048;
        const u16* rB = lB + sel * 4096;
        bf16x8 af[4], bf[2];
#pragma unroll
        for (int i = 0; i < 4; ++i)
            af[i] = *(const bf16x8*)(rA + (i * 16 + m0) * 32 + kqs);
#pragma unroll
        for (int j = 0; j < 2; ++j)
            bf[j] = *(const bf16x8*)(rB + (wc + j * 16 + m0) * 32 + kqs);
#pragma unroll
        for (int i = 0; i < 4; ++i)
#pragma unroll
            for (int j = 0; j < 2; ++j)
                acc[i][j] = __builtin_amdgcn_mfma_f32_16x16x32_bf16(af[i], bf[j],
                                                                    acc[i][j], 0, 0, 0);
    };

    STAGE(0, 0);
    for (int t = 0; t < 15; ++t) {
        const int sel = t & 1;
        STAGE((t + 1) << 5, sel ^ 1);                      // prefetch next tile
        asm volatile("s_waitcnt vmcnt(3)" ::: "memory");
        __builtin_amdgcn_s_barrier();
        COMPUTE(sel);
        asm volatile("s_waitcnt lgkmcnt(0)" ::: "memory");
        __builtin_amdgcn_s_barrier();
    }
    asm volatile("s_waitcnt vmcnt(0)" ::: "memory");       // t = 15
    __builtin_amdgcn_s_barrier();
    COMPUTE(1);
}

// ================= phase C body: h1 = relu(C1s + mean(P1fp8[nbrs]) + b1) =========
static __device__ void agg_h1_body(int n, int l, const u8* __restrict__ P1,
                                   const u16* __restrict__ C1s,
                                   const u16* __restrict__ b1c,
                                   const int* __restrict__ cnt,
                                   const int* __restrict__ bucket,
                                   const int* __restrict__ nspill,
                                   const int* __restrict__ spill,
                                   u16* __restrict__ h1) {
    const int c = cnt[n];
    const int inb = c < CAP ? c : CAP;
    const int* bk = bucket + (long)n * CAP;
    float a0 = 0.f, a1 = 0.f, a2 = 0.f, a3 = 0.f;
    float a4 = 0.f, a5 = 0.f, a6 = 0.f, a7 = 0.f;
    int e = 0;
    for (; e + 7 < inb; e += 8) {
        u32x2 w[8];
#pragma unroll
        for (int q = 0; q < 8; ++q) {
            int s = bk[e + q];
            w[q] = *(const u32x2*)(P1 + (long)s * 512 + l * 8);
        }
#pragma unroll
        for (int q = 0; q < 8; ++q) {
            floatx2 f0 = __builtin_amdgcn_cvt_pk_f32_fp8(w[q][0], false);
            floatx2 f1 = __builtin_amdgcn_cvt_pk_f32_fp8(w[q][0], true);
            floatx2 f2 = __builtin_amdgcn_cvt_pk_f32_fp8(w[q][1], false);
            floatx2 f3 = __builtin_amdgcn_cvt_pk_f32_fp8(w[q][1], true);
            a0 += f0[0]; a1 += f0[1]; a2 += f1[0]; a3 += f1[1];
            a4 += f2[0]; a5 += f2[1]; a6 += f3[0]; a7 += f3[1];
        }
    }
    for (; e + 3 < inb; e += 4) {
        u32x2 w[4];
#pragma unroll
        for (int q = 0; q < 4; ++q) {
            int s = bk[e + q];
            w[q] = *(const u32x2*)(P1 + (long)s * 512 + l * 8);
        }
#pragma unroll
        for (int q = 0; q < 4; ++q) {
            floatx2 f0 = __builtin_amdgcn_cvt_pk_f32_fp8(w[q][0], false);
            floatx2 f1 = __builtin_amdgcn_cvt_pk_f32_fp8(w[q][0], true);
            floatx2 f2 = __builtin_amdgcn_cvt_pk_f32_fp8(w[q][1], false);
            floatx2 f3 = __builtin_amdgcn_cvt_pk_f32_fp8(w[q][1], true);
            a0 += f0[0]; a1 += f0[1]; a2 += f1[0]; a3 += f1[1];
            a4 += f2[0]; a5 += f2[1]; a6 += f3[0]; a7 += f3[1];
        }
    }
    for (; e < inb; ++e) {
        int s = bk[e];
        u32x2 w = *(const u32x2*)(P1 + (long)s * 512 + l * 8);
        floatx2 f0 = __builtin_amdgcn_cvt_pk_f32_fp8(w[0], false);
        floatx2 f1 = __builtin_amdgcn_cvt_pk_f32_fp8(w[0], true);
        floatx2 f2 = __builtin_amdgcn_cvt_pk_f32_fp8(w[1], false);
        floatx2 f3 = __builtin_amdgcn_cvt_pk_f32_fp8(w[1], true);
        a0 += f0[0]; a1 += f0[1]; a2 += f1[0]; a3 += f1[1];
        a4 += f2[0]; a5 += f2[1]; a6 += f3[0]; a7 += f3[1];
    }
    const int ns = *nspill;
    if (ns > 0) {
        int lim = ns < SPILLMAX ? ns : SPILLMAX;
        for (int q = 0; q < lim; ++q) {
            if (spill[2 * q] == n) {
                int s = spill[2 * q + 1];
                u32x2 w = *(const u32x2*)(P1 + (long)s * 512 + l * 8);
                floatx2 f0 = __builtin_amdgcn_cvt_pk_f32_fp8(w[0], false);
                floatx2 f1 = __builtin_amdgcn_cvt_pk_f32_fp8(w[0], true);
                floatx2 f2 = __builtin_amdgcn_cvt_pk_f32_fp8(w[1], false);
                floatx2 f3 = __builtin_amdgcn_cvt_pk_f32_fp8(w[1], true);
                a0 += f0[0]; a1 += f0[1]; a2 += f1[0]; a3 += f1[1];
                a4 += f2[0]; a5 += f2[1]; a6 += f3[0]; a7 += f3[1];
            }
        }
    }
    float inv = 1.0f / (float)(c > 1 ? c : 1);
    us8 sf = *(const us8*)(C1s + (long)n * 512 + l * 8);
    us8 bv = *(const us8*)(b1c + l * 8);
    us8 o;
    o[0] = f2b(fmaxf(b2f(sf[0]) + a0 * inv + b2f(bv[0]), 0.f));
    o[1] = f2b(fmaxf(b2f(sf[1]) + a1 * inv + b2f(bv[1]), 0.f));
    o[2] = f2b(fmaxf(b2f(sf[2]) + a2 * inv + b2f(bv[2]), 0.f));
    o[3] = f2b(fmaxf(b2f(sf[3]) + a3 * inv + b2f(bv[3]), 0.f));
    o[4] = f2b(fmaxf(b2f(sf[4]) + a4 * inv + b2f(bv[4]), 0.f));
    o[5] = f2b(fmaxf(b2f(sf[5]) + a5 * inv + b2f(bv[5]), 0.f));
    o[6] = f2b(fmaxf(b2f(sf[6]) + a6 * inv + b2f(bv[6]), 0.f));
    o[7] = f2b(fmaxf(b2f(sf[7]) + a7 * inv + b2f(bv[7]), 0.f));
    *(us8*)(h1 + (long)n * 512 + l * 8) = o;
}

// ================= phase E body: out = C2s + mean(P2[nbrs]) + b2 =================
static __device__ void agg_out_body(int n, int l, const u16* __restrict__ P2,
                                    const u16* __restrict__ C2s,
                                    const u16* __restrict__ b2c,
                                    const int* __restrict__ cnt,
                                    const int* __restrict__ bucket,
                                    const int* __restrict__ nspill,
                                    const int* __restrict__ spill,
                                    void* __restrict__ outv,
                                    const int* __restrict__ flags) {
    const int c = cnt[n];
    const int inb = c < CAP ? c : CAP;
    const int* bk = bucket + (long)n * CAP;
    float a0 = 0.f, a1 = 0.f;
    int e = 0;
    for (; e + 3 < inb; e += 4) {
        int s0 = bk[e], s1 = bk[e + 1], s2 = bk[e + 2], s3 = bk[e + 3];
        us2 v0 = *(const us2*)(P2 + (long)s0 * 128 + l * 2);
        us2 v1 = *(const us2*)(P2 + (long)s1 * 128 + l * 2);
        us2 v2 = *(const us2*)(P2 + (long)s2 * 128 + l * 2);
        us2 v3 = *(const us2*)(P2 + (long)s3 * 128 + l * 2);
        a0 += (b2f(v0[0]) + b2f(v1[0])) + (b2f(v2[0]) + b2f(v3[0]));
        a1 += (b2f(v0[1]) + b2f(v1[1])) + (b2f(v2[1]) + b2f(v3[1]));
    }
    for (; e < inb; ++e) {
        int s0 = bk[e];
        us2 v0 = *(const us2*)(P2 + (long)s0 * 128 + l * 2);
        a0 += b2f(v0[0]); a1 += b2f(v0[1]);
    }
    const int ns = *nspill;
    if (ns > 0) {
        int lim = ns < SPILLMAX ? ns : SPILLMAX;
        for (int q = 0; q < lim; ++q) {
            if (spill[2 * q] == n) {
                int s0 = spill[2 * q + 1];
                us2 v0 = *(const us2*)(P2 + (long)s0 * 128 + l * 2);
                a0 += b2f(v0[0]); a1 += b2f(v0[1]);
            }
        }
    }
    float inv = 1.0f / (float)(c > 1 ? c : 1);
    us2 sf = *(const us2*)(C2s + (long)n * 128 + l * 2);
    us2 bv = *(const us2*)(b2c + l * 2);
    float o0 = b2f(sf[0]) + a0 * inv + b2f(bv[0]);
    float o1 = b2f(sf[1]) + a1 * inv + b2f(bv[1]);
    if (flags[0]) {
        float* o = (float*)outv + (long)n * 128 + l * 2;
        o[0] = o0; o[1] = o1;
    } else {
        us2 ob; ob[0] = f2b(o0); ob[1] = f2b(o1);
        *(us2*)((u16*)outv + (long)n * 128 + l * 2) = ob;
    }
}

// ================= fused persistent kernel: A |sync| B |sync| C |sync| D |sync| E =
__global__ __launch_bounds__(256, 3) void k_fused(
    const int* __restrict__ src, const int* __restrict__ dst, int E, int Nn,
    int* __restrict__ cnt, int* __restrict__ bucket,
    int* __restrict__ nspill, int* __restrict__ spill,
    const void* __restrict__ h, const void* __restrict__ W1,
    const void* __restrict__ b1v, const void* __restrict__ W2,
    const void* __restrict__ b2v,
    u16* __restrict__ Hb, u16* __restrict__ W1T, u16* __restrict__ W2T,
    u16* __restrict__ b1c, u16* __restrict__ b2c, int* __restrict__ flags,
    u16* __restrict__ C1s, u8* __restrict__ P1, u16* __restrict__ h1,
    u16* __restrict__ C2s, u16* __restrict__ P2, void* __restrict__ outv,
    int* __restrict__ grp_arr, int* __restrict__ root, int* __restrict__ grp_gen,
    int nFill, int nHb, int mt64) {
    __shared__ __align__(16) u16 smem[12288];  // 24 KB: lA(4K u16) + lB(8K u16)
    __shared__ int sh;
    u16* lA = smem;
    u16* lB = smem + 4096;
    const int tid = threadIdx.x;
    const int ln = tid & 63;
    const int wv = tid >> 6;

    // ---- phase A: buckets + conversions ----
    const int nA = nFill + nHb + 641;
    for (int vb = blockIdx.x; vb < nA; vb += NBLK) {
        __syncthreads();  // protect smem/sh reuse across iterations
        d1_body(vb, src, dst, E, Nn, cnt, bucket, nspill, spill,
                h, W1, b1v, W2, b2v, Hb, W1T, W2T, b1c, b2c, flags,
                nFill, nHb, smem, &sh);
    }
    grid_sync(grp_arr, root, grp_gen);

    // ---- phase B: GEMM1 [C1s(bf16) | P1(fp8)] = Hb @ W1T^T, 64x128 tiles ----
    const int nt1 = mt64 * 8;
    for (int L = blockIdx.x; L < nt1; L += NBLK) {
        __syncthreads();  // previous tile's LDS reads fully retired
        const int T = xcd_swz(L, nt1);
        const int by = T & 7;
        const int bcol = by * 128;
        const long brow = (long)(T >> 3) * 64;
        floatx4 acc[4][2];
        gemm_acc64(Hb, W1T, brow, bcol, acc, lA, lB);
        const int wc = wv * 32;
        const int m0 = ln & 15;
        const int q4 = (ln >> 4) * 4;
        if (by < 4) {  // self half -> bf16
#pragma unroll
            for (int i = 0; i < 4; ++i)
#pragma unroll
                for (int r = 0; r < 4; ++r) {
                    long row = brow + i * 16 + q4 + r;
                    if (row < Nn) {
#pragma unroll
                        for (int j = 0; j < 2; ++j)
                            C1s[row * 512 + (bcol + wc + j * 16 + m0)] =
                                f2b(acc[i][j][r]);
                    }
                }
        } else {       // agg half -> fp8 e4m3
            const int coff = bcol - 512;
#pragma unroll
            for (int i = 0; i < 4; ++i)
#pragma unroll
                for (int r = 0; r < 4; ++r) {
                    long row = brow + i * 16 + q4 + r;
                    if (row < Nn) {
#pragma unroll
                        for (int j = 0; j < 2; ++j) {
                            float v = acc[i][j][r];
                            int pk = __builtin_amdgcn_cvt_pk_fp8_f32(v, v, 0, false);
                            P1[row * 512 + (coff + wc + j * 16 + m0)] = (u8)(pk & 0xff);
                        }
                    }
                }
        }
    }
    grid_sync(grp_arr, root, grp_gen);

    // ---- phase C: h1 = relu(C1s + mean(P1[nbrs]) + b1), wave-per-node ----
    const int nNd = (Nn + 3) >> 2;
    for (int vb = blockIdx.x; vb < nNd; vb += NBLK) {
        int n = vb * 4 + wv;
        if (n < Nn) agg_h1_body(n, ln, P1, C1s, b1c, cnt, bucket, nspill, spill, h1);
    }
    grid_sync(grp_arr, root, grp_gen);

    // ---- phase D: GEMM2 [C2s|P2] = h1 @ W2T^T, 64x128 tiles ----
    const int nt2 = mt64 * 2;
    for (int L = blockIdx.x; L < nt2; L += NBLK) {
        __syncthreads();
        const int T = xcd_swz(L, nt2);
        const int by2 = T & 1;
        const long brow = (long)(T >> 1) * 64;
        floatx4 acc[4][2];
        gemm_acc64(h1, W2T, brow, by2 * 128, acc, lA, lB);
        u16* C = by2 ? P2 : C2s;
        const int wc = wv * 32;
        const int m0 = ln & 15;
        const int q4 = (ln >> 4) * 4;
#pragma unroll
        for (int i = 0; i < 4; ++i)
#pragma unroll
            for (int r = 0; r < 4; ++r) {
                long row = brow + i * 16 + q4 + r;
                if (row < Nn) {
#pragma unroll
                    for (int j = 0; j < 2; ++j)
                        C[row * 128 + (wc + j * 16 + m0)] = f2b(acc[i][j][r]);
                }
            }
    }
    grid_sync(grp_arr, root, grp_gen);

    // ---- phase E: out = C2s + mean(P2[nbrs]) + b2 ----
    for (int vb = blockIdx.x; vb < nNd; vb += NBLK) {
        int n = vb * 4 + wv;
        if (n < Nn) agg_out_body(n, ln, P2, C2s, b2c, cnt, bucket, nspill, spill,
                                 outv, flags);
    }
}

// ================= launch ========================================================
extern "C" void kernel_launch(void* const* d_in, const int* in_sizes, int n_in,
                              void* d_out, int out_size, void* d_ws, size_t ws_size,
                              hipStream_t stream) {
    const int D = 512, NCLS = 128;
    const int Nn = in_sizes[0] / D;            // 10000
    const int E  = in_sizes[5];                // 160000
    const int mtiles = (Nn + 127) / 128;       // 79
    const int mt64 = (Nn + 63) / 64;           // 157
    const int Mpad = mtiles * 128;             // 10112
    const int nFill = (E + 255) / 256;         // 625
    const int nHb = (Nn * D / 8 + 255) / 256;  // 2500

    const int* src = (const int*)d_in[5];
    const int* dst = (const int*)d_in[6];

    char* p = (char*)d_ws;
    u16* Hb  = (u16*)p; p += (size_t)Mpad * D * 2;
    u16* h1  = (u16*)p; p += (size_t)Mpad * D * 2;
    u16* C1s = (u16*)p; p += (size_t)Mpad * D * 2;
    u8*  P1  = (u8*)p;  p += (size_t)Mpad * D;        // fp8 e4m3
    u16* C2s = (u16*)p; p += (size_t)Mpad * NCLS * 2;
    u16* P2  = (u16*)p; p += (size_t)Mpad * NCLS * 2;
    u16* W1T = (u16*)p; p += (size_t)1024 * D * 2;
    u16* W2T = (u16*)p; p += (size_t)256 * D * 2;
    u16* b1c = (u16*)p; p += 1024;
    u16* b2c = (u16*)p; p += 1024;
    int* flags  = (int*)p; p += 256;
    int* cnt    = (int*)p; p += (size_t)(Nn + 1024) * 4;
    int* nspill  = cnt + Nn;
    int* grp_arr = cnt + Nn + 64;          // 8 lines, 32 ints (128 B) apart
    int* root    = cnt + Nn + 64 + 256;    // own line
    int* grp_gen = cnt + Nn + 64 + 320;    // 8 lines
    int* bucket = (int*)p; p += (size_t)Nn * CAP * 4;
    int* spill  = (int*)p; p += (size_t)SPILLMAX * 2 * 4;

    hipMemsetAsync(cnt, 0, (size_t)(Nn + 1024) * 4, stream);

    k_fused<<<NBLK, 256, 0, stream>>>(
        src, dst, E, Nn, cnt, bucket, nspill, spill,
        d_in[0], d_in[1], d_in[2], d_in[3], d_in[4],
        Hb, W1T, W2T, b1c, b2c, flags,
        C1s, P1, h1, C2s, P2, d_out,
        grp_arr, root, grp_gen, nFill, nHb, mt64);
}

// Round 9
// 143.152 us; speedup vs baseline: 1.9582x; 1.9582x over previous
//
#include <hip/hip_runtime.h>

typedef unsigned short u16;
typedef unsigned char u8;
typedef __attribute__((ext_vector_type(2))) float floatx2;
typedef __attribute__((ext_vector_type(4))) float floatx4;
typedef __attribute__((ext_vector_type(8))) __bf16 bf16x8;
typedef __attribute__((ext_vector_type(2))) unsigned short us2;
typedef __attribute__((ext_vector_type(4))) unsigned short us4;
typedef __attribute__((ext_vector_type(8))) unsigned short us8;
typedef __attribute__((ext_vector_type(2))) unsigned int u32x2;

static __device__ __forceinline__ float b2f(u16 v) {
    union { unsigned u; float f; } x; x.u = ((unsigned)v) << 16; return x.f;
}
static __device__ __forceinline__ u16 f2b(float f) {
    union { float f; unsigned u; } x; x.f = f;
    unsigned u = x.u;
    return (u16)((u + 0x7fffu + ((u >> 16) & 1u)) >> 16);
}

#define GLOAD_LDS16(g, l) __builtin_amdgcn_global_load_lds( \
    (const __attribute__((address_space(1))) void*)(g),     \
    (__attribute__((address_space(3))) void*)(l), 16, 0, 0)

#define CAP 64
#define SPILLMAX 4096

// Per-block dtype self-detection: P(misdetect fp32) ~ 1e-65.
static __device__ __forceinline__ int detect_blk(const u16* __restrict__ p,
                                                 int nelem, int* sh) {
    if (threadIdx.x == 0) *sh = 0;
    __syncthreads();
    const int lim = nelem < 512 ? nelem : 512;
    int found = 0;
    for (int j = threadIdx.x; 2 * j < lim; j += 256) {
        unsigned v = p[2 * j] & 0x7fffu;
        if (v >= 0x4280u) found = 1;  // |bf16(bits)| >= 64.0
    }
    if (found) atomicOr(sh, 1);
    __syncthreads();
    return *sh;
}

// Bijective XCD-chunked swizzle (m204).
static __device__ __forceinline__ int xcd_swz(int L, int nwg) {
    const int q = nwg >> 3, r = nwg & 7;
    const int x = L & 7, i = L >> 3;
    return (x < r ? x * (q + 1) : r * (q + 1) + (x - r) * q) + i;
}

// ================= D1: buckets + all conversions (R3 form, merged) ===============
__global__ __launch_bounds__(256) void k_d1(
    const int* __restrict__ src, const int* __restrict__ dst, int E, int Nn,
    int* __restrict__ cnt, int* __restrict__ bucket,
    int* __restrict__ nspill, int* __restrict__ spill,
    const void* __restrict__ h, const void* __restrict__ W1,
    const void* __restrict__ b1, const void* __restrict__ W2,
    const void* __restrict__ b2,
    u16* __restrict__ Hb, u16* __restrict__ W1T, u16* __restrict__ W2T,
    u16* __restrict__ b1c, u16* __restrict__ b2c, int* __restrict__ flags,
    int nFill, int nHb) {
    __shared__ u16 tile[32][33];
    __shared__ int sh;
    const int b = blockIdx.x;
    const int t = threadIdx.x;

    if (b < nFill) {  // -------- bucket fill --------
        int e = b * 256 + t;
        if (e < E) {
            int d = dst[e], s = src[e];
            if ((unsigned)d < (unsigned)Nn && (unsigned)s < (unsigned)Nn) {
                int p = atomicAdd(&cnt[d], 1);
                if (p < CAP) bucket[d * CAP + p] = s;
                else {
                    int q = atomicAdd(nspill, 1);
                    if (q < SPILLMAX) { spill[2 * q] = d; spill[2 * q + 1] = s; }
                }
            }
        }
        return;
    }
    if (b < nFill + nHb) {  // -------- Hb cvt --------
        const int f = detect_blk((const u16*)h, Nn * 512, &sh);
        int i = ((b - nFill) * 256 + t) * 8;
        if (i >= Nn * 512) return;
        if (f) {
            const floatx4* s = (const floatx4*)((const float*)h + i);
            floatx4 v0 = s[0], v1 = s[1];
            us8 o;
            o[0] = f2b(v0[0]); o[1] = f2b(v0[1]); o[2] = f2b(v0[2]); o[3] = f2b(v0[3]);
            o[4] = f2b(v1[0]); o[5] = f2b(v1[1]); o[6] = f2b(v1[2]); o[7] = f2b(v1[3]);
            *(us8*)(Hb + i) = o;
        } else {
            *(us8*)(Hb + i) = *(const us8*)((const u16*)h + i);
        }
        return;
    }
    if (b < nFill + nHb + 512) {  // -------- W1 [1024,512] -> W1T [1024,512] --------
        const int f = detect_blk((const u16*)W1, 1024 * 512, &sh);
        int sub = b - nFill - nHb;
        int half = sub >> 8, idx = sub & 255;
        const int bx = (idx & 15) * 32, by = (idx >> 4) * 32;
        const int koff = half * 512, noff = half * 512;
        const int tx = t & 31, ty = t >> 5;
        for (int i = ty; i < 32; i += 8) {
            long id = (long)(koff + by + i) * 512 + (bx + tx);
            tile[i][tx] = f ? f2b(((const float*)W1)[id]) : ((const u16*)W1)[id];
        }
        __syncthreads();
        for (int i = ty; i < 32; i += 8)
            W1T[(long)(noff + bx + i) * 512 + (by + tx)] = tile[tx][i];
        return;
    }
    if (b < nFill + nHb + 640) {  // -------- W2 [1024,128] -> W2T [256,512] --------
        const int f = detect_blk((const u16*)W2, 1024 * 128, &sh);
        int sub = b - nFill - nHb - 512;
        int half = sub >> 6, idx = sub & 63;
        const int bx = (idx & 3) * 32, by = (idx >> 2) * 32;
        const int koff = half * 512, noff = half * 128;
        const int tx = t & 31, ty = t >> 5;
        for (int i = ty; i < 32; i += 8) {
            long id = (long)(koff + by + i) * 128 + (bx + tx);
            tile[i][tx] = f ? f2b(((const float*)W2)[id]) : ((const u16*)W2)[id];
        }
        __syncthreads();
        for (int i = ty; i < 32; i += 8)
            W2T[(long)(noff + bx + i) * 512 + (by + tx)] = tile[tx][i];
        return;
    }
    // -------- biases + out-dtype flag --------
    {
        const int f1 = detect_blk((const u16*)b1, 512, &sh);
        for (int i = t; i < 512; i += 256)
            b1c[i] = f1 ? f2b(((const float*)b1)[i]) : ((const u16*)b1)[i];
        const int f2 = detect_blk((const u16*)b2, 128, &sh);
        if (t < 128)
            b2c[t] = f2 ? f2b(((const float*)b2)[t]) : ((const u16*)b2)[t];
        const int fh = detect_blk((const u16*)h, Nn * 512, &sh);
        if (t == 0) flags[0] = fh;
    }
}

// ================= 64x128 GEMM core — BK=64, 2-phase dbuf, XOR swizzle ===========
// R8 post-mortem: with 64 B LDS rows (BK=32) only 4 16-B chunks exist, so 64
// lanes MUST alias 16-way on ds_read_b128 (pigeonhole) — R7's swizzle null.
// BK=64 -> 128 B rows = 8 chunks; XOR pos = chunk ^ (row&7) spreads reads to
// 8-way (m136: 5.69x -> 2.94x), AND k-iters halve 16 -> 8, halving the
// per-iteration barrier+vmcnt drain count (the dominant cost per R6 algebra).
// Swizzle per rule #21: LDS dest linear (global_load_lds writes base+lane*16B);
// the GLOBAL source chunk is pre-swizzled; reads apply the same XOR.
// Each tile computes its two K=32 halves in the old order -> per-output K
// order identical to all previous cores -> bit-identical results.
__device__ __forceinline__ void gemm_acc64(const u16* __restrict__ A,
                                           const u16* __restrict__ Bt,
                                           long brow, int bobs,
                                           floatx4 acc[4][2], u16* lA, u16* lB) {
    const int tid = threadIdx.x;
    const int wv = tid >> 6;
    const int ln = tid & 63;
    const int rlow = ln >> 3;          // 0..7: row-within-8-group at staging
    const int cpos = ln & 7;           // 0..7: LDS chunk position at staging
    const int csrc = (cpos ^ rlow) * 8;  // pre-swizzled source chunk (u16 units)
    const int m0 = ln & 15;
    const int g4 = ln >> 4;            // 0..3: K-quad group at read
    const int wc = wv * 32;

#pragma unroll
    for (int i = 0; i < 4; ++i)
#pragma unroll
        for (int j = 0; j < 2; ++j) acc[i][j] = (floatx4){0.f, 0.f, 0.f, 0.f};

    auto STAGE = [&](int kt, int sel) {
        // A: wave wv stages rows wv*16 .. wv*16+15 (2 loads/lane)
#pragma unroll
        for (int q = 0; q < 2; ++q) {
            const int r = wv * 16 + q * 8 + rlow;
            GLOAD_LDS16(A + (brow + r) * 512 + kt + csrc,
                        lA + sel * 4096 + wv * 1024 + q * 512);
        }
        // B: wave wv stages rows wv*32 .. wv*32+31 (4 loads/lane)
#pragma unroll
        for (int q = 0; q < 4; ++q) {
            const int r = wv * 32 + q * 8 + rlow;
            GLOAD_LDS16(Bt + (long)(bobs + r) * 512 + kt + csrc,
                        lB + sel * 8192 + wv * 2048 + q * 512);
        }
    };
    auto COMPUTE = [&](int sel) {
        const u16* rA = lA + sel * 4096;
        const u16* rB = lB + sel * 8192;
#pragma unroll
        for (int kk = 0; kk < 2; ++kk) {
            const int p = ((kk * 4 + g4) ^ (m0 & 7)) * 8;  // swizzled read pos
            bf16x8 af[4], bf[2];
#pragma unroll
            for (int i = 0; i < 4; ++i)
                af[i] = *(const bf16x8*)(rA + (i * 16 + m0) * 64 + p);
#pragma unroll
            for (int j = 0; j < 2; ++j)
                bf[j] = *(const bf16x8*)(rB + (wc + j * 16 + m0) * 64 + p);
#pragma unroll
            for (int i = 0; i < 4; ++i)
#pragma unroll
                for (int j = 0; j < 2; ++j)
                    acc[i][j] = __builtin_amdgcn_mfma_f32_16x16x32_bf16(
                        af[i], bf[j], acc[i][j], 0, 0, 0);
        }
    };

    STAGE(0, 0);
    for (int t = 0; t < 7; ++t) {                          // 8 tiles of K=64
        const int sel = t & 1;
        STAGE((t + 1) << 6, sel ^ 1);                      // prefetch next tile
        asm volatile("s_waitcnt vmcnt(6)" ::: "memory");   // tile t resident
        __builtin_amdgcn_s_barrier();
        COMPUTE(sel);
        asm volatile("s_waitcnt lgkmcnt(0)" ::: "memory");
        __builtin_amdgcn_s_barrier();
    }
    asm volatile("s_waitcnt vmcnt(0)" ::: "memory");       // t = 7
    __builtin_amdgcn_s_barrier();
    COMPUTE(1);
}

// ================= D2: GEMM1 64x128 ([C1s(bf16) | P1(fp8)] = Hb @ W1T^T) =========
__global__ __launch_bounds__(256) void k_gemm1_64(
    const u16* __restrict__ A, const u16* __restrict__ Bt,
    u16* __restrict__ C1s, u8* __restrict__ P1, int Mstore) {
    __shared__ __align__(16) u16 lA[2 * 64 * 64];    // 16 KB
    __shared__ __align__(16) u16 lB[2 * 128 * 64];   // 32 KB
    const int L = blockIdx.y * gridDim.x + blockIdx.x;
    const int T = xcd_swz(L, gridDim.x * gridDim.y);
    const int by = T & 7;                // col slice 0..7 (128 cols each)
    const int bcol = by * 128;
    const long brow = (long)(T >> 3) * 64;
    floatx4 acc[4][2];
    gemm_acc64(A, Bt, brow, bcol, acc, lA, lB);

    const int ln = threadIdx.x & 63;
    const int wv = threadIdx.x >> 6;
    const int wc = wv * 32;
    const int m0 = ln & 15;
    const int q4 = (ln >> 4) * 4;
    if (by < 4) {  // self half (cols 0..511) -> bf16
#pragma unroll
        for (int i = 0; i < 4; ++i)
#pragma unroll
            for (int r = 0; r < 4; ++r) {
                long row = brow + i * 16 + q4 + r;
                if (row < Mstore) {
#pragma unroll
                    for (int j = 0; j < 2; ++j)
                        C1s[row * 512 + (bcol + wc + j * 16 + m0)] = f2b(acc[i][j][r]);
                }
            }
    } else {       // agg half (cols 512..1023) -> fp8 e4m3
        const int coff = bcol - 512;
#pragma unroll
        for (int i = 0; i < 4; ++i)
#pragma unroll
            for (int r = 0; r < 4; ++r) {
                long row = brow + i * 16 + q4 + r;
                if (row < Mstore) {
#pragma unroll
                    for (int j = 0; j < 2; ++j) {
                        float v = acc[i][j][r];
                        int pk = __builtin_amdgcn_cvt_pk_fp8_f32(v, v, 0, false);
                        P1[row * 512 + (coff + wc + j * 16 + m0)] = (u8)(pk & 0xff);
                    }
                }
            }
    }
}

// ================= D4: GEMM2 64x128 ([C2s|P2] = h1 @ W2T^T) ======================
__global__ __launch_bounds__(256) void k_gemm2_64(
    const u16* __restrict__ A, const u16* __restrict__ Bt,
    u16* __restrict__ C2s, u16* __restrict__ P2, int Mstore) {
    __shared__ __align__(16) u16 lA[2 * 64 * 64];
    __shared__ __align__(16) u16 lB[2 * 128 * 64];
    const int L = blockIdx.y * gridDim.x + blockIdx.x;
    const int T = xcd_swz(L, gridDim.x * gridDim.y);
    const int by = T & 1;
    const long brow = (long)(T >> 1) * 64;
    floatx4 acc[4][2];
    gemm_acc64(A, Bt, brow, by * 128, acc, lA, lB);

    u16* C = by ? P2 : C2s;
    const int ln = threadIdx.x & 63;
    const int wv = threadIdx.x >> 6;
    const int wc = wv * 32;
    const int m0 = ln & 15;
    const int q4 = (ln >> 4) * 4;
#pragma unroll
    for (int i = 0; i < 4; ++i)
#pragma unroll
        for (int r = 0; r < 4; ++r) {
            long row = brow + i * 16 + q4 + r;
            if (row < Mstore) {
#pragma unroll
                for (int j = 0; j < 2; ++j)
                    C[row * 128 + (wc + j * 16 + m0)] = f2b(acc[i][j][r]);
            }
        }
}

// ================= D3: h1 = relu(C1s + mean(P1fp8[nbrs]) + b1) ===================
__global__ __launch_bounds__(256) void agg_h1(const u8* __restrict__ P1,
                                              const u16* __restrict__ C1s,
                                              const u16* __restrict__ b1c,
                                              const int* __restrict__ cnt,
                                              const int* __restrict__ bucket,
                                              const int* __restrict__ nspill,
                                              const int* __restrict__ spill,
                                              u16* __restrict__ h1, int Nn) {
    const int n = blockIdx.x * 4 + (threadIdx.x >> 6);
    const int l = threadIdx.x & 63;
    if (n >= Nn) return;
    const int c = cnt[n];
    const int inb = c < CAP ? c : CAP;
    const int* bk = bucket + (long)n * CAP;
    float a0 = 0.f, a1 = 0.f, a2 = 0.f, a3 = 0.f;
    float a4 = 0.f, a5 = 0.f, a6 = 0.f, a7 = 0.f;
    int e = 0;
    for (; e + 7 < inb; e += 8) {
        u32x2 w[8];
#pragma unroll
        for (int q = 0; q < 8; ++q) {
            int s = bk[e + q];
            w[q] = *(const u32x2*)(P1 + (long)s * 512 + l * 8);
        }
#pragma unroll
        for (int q = 0; q < 8; ++q) {
            floatx2 f0 = __builtin_amdgcn_cvt_pk_f32_fp8(w[q][0], false);
            floatx2 f1 = __builtin_amdgcn_cvt_pk_f32_fp8(w[q][0], true);
            floatx2 f2 = __builtin_amdgcn_cvt_pk_f32_fp8(w[q][1], false);
            floatx2 f3 = __builtin_amdgcn_cvt_pk_f32_fp8(w[q][1], true);
            a0 += f0[0]; a1 += f0[1]; a2 += f1[0]; a3 += f1[1];
            a4 += f2[0]; a5 += f2[1]; a6 += f3[0]; a7 += f3[1];
        }
    }
    for (; e + 3 < inb; e += 4) {
        u32x2 w[4];
#pragma unroll
        for (int q = 0; q < 4; ++q) {
            int s = bk[e + q];
            w[q] = *(const u32x2*)(P1 + (long)s * 512 + l * 8);
        }
#pragma unroll
        for (int q = 0; q < 4; ++q) {
            floatx2 f0 = __builtin_amdgcn_cvt_pk_f32_fp8(w[q][0], false);
            floatx2 f1 = __builtin_amdgcn_cvt_pk_f32_fp8(w[q][0], true);
            floatx2 f2 = __builtin_amdgcn_cvt_pk_f32_fp8(w[q][1], false);
            floatx2 f3 = __builtin_amdgcn_cvt_pk_f32_fp8(w[q][1], true);
            a0 += f0[0]; a1 += f0[1]; a2 += f1[0]; a3 += f1[1];
            a4 += f2[0]; a5 += f2[1]; a6 += f3[0]; a7 += f3[1];
        }
    }
    for (; e < inb; ++e) {
        int s = bk[e];
        u32x2 w = *(const u32x2*)(P1 + (long)s * 512 + l * 8);
        floatx2 f0 = __builtin_amdgcn_cvt_pk_f32_fp8(w[0], false);
        floatx2 f1 = __builtin_amdgcn_cvt_pk_f32_fp8(w[0], true);
        floatx2 f2 = __builtin_amdgcn_cvt_pk_f32_fp8(w[1], false);
        floatx2 f3 = __builtin_amdgcn_cvt_pk_f32_fp8(w[1], true);
        a0 += f0[0]; a1 += f0[1]; a2 += f1[0]; a3 += f1[1];
        a4 += f2[0]; a5 += f2[1]; a6 += f3[0]; a7 += f3[1];
    }
    const int ns = *nspill;
    if (ns > 0) {
        int lim = ns < SPILLMAX ? ns : SPILLMAX;
        for (int q = 0; q < lim; ++q) {
            if (spill[2 * q] == n) {
                int s = spill[2 * q + 1];
                u32x2 w = *(const u32x2*)(P1 + (long)s * 512 + l * 8);
                floatx2 f0 = __builtin_amdgcn_cvt_pk_f32_fp8(w[0], false);
                floatx2 f1 = __builtin_amdgcn_cvt_pk_f32_fp8(w[0], true);
                floatx2 f2 = __builtin_amdgcn_cvt_pk_f32_fp8(w[1], false);
                floatx2 f3 = __builtin_amdgcn_cvt_pk_f32_fp8(w[1], true);
                a0 += f0[0]; a1 += f0[1]; a2 += f1[0]; a3 += f1[1];
                a4 += f2[0]; a5 += f2[1]; a6 += f3[0]; a7 += f3[1];
            }
        }
    }
    float inv = 1.0f / (float)(c > 1 ? c : 1);
    us8 sf = *(const us8*)(C1s + (long)n * 512 + l * 8);
    us8 bv = *(const us8*)(b1c + l * 8);
    us8 o;
    o[0] = f2b(fmaxf(b2f(sf[0]) + a0 * inv + b2f(bv[0]), 0.f));
    o[1] = f2b(fmaxf(b2f(sf[1]) + a1 * inv + b2f(bv[1]), 0.f));
    o[2] = f2b(fmaxf(b2f(sf[2]) + a2 * inv + b2f(bv[2]), 0.f));
    o[3] = f2b(fmaxf(b2f(sf[3]) + a3 * inv + b2f(bv[3]), 0.f));
    o[4] = f2b(fmaxf(b2f(sf[4]) + a4 * inv + b2f(bv[4]), 0.f));
    o[5] = f2b(fmaxf(b2f(sf[5]) + a5 * inv + b2f(bv[5]), 0.f));
    o[6] = f2b(fmaxf(b2f(sf[6]) + a6 * inv + b2f(bv[6]), 0.f));
    o[7] = f2b(fmaxf(b2f(sf[7]) + a7 * inv + b2f(bv[7]), 0.f));
    *(us8*)(h1 + (long)n * 512 + l * 8) = o;
}

// ================= D5: out = C2s + mean(P2[nbrs]) + b2 ===========================
__global__ __launch_bounds__(256) void agg_out(const u16* __restrict__ P2,
                                               const u16* __restrict__ C2s,
                                               const u16* __restrict__ b2c,
                                               const int* __restrict__ cnt,
                                               const int* __restrict__ bucket,
                                               const int* __restrict__ nspill,
                                               const int* __restrict__ spill,
                                               void* __restrict__ outv, int Nn,
                                               const int* __restrict__ flags) {
    const int n = blockIdx.x * 4 + (threadIdx.x >> 6);
    const int l = threadIdx.x & 63;
    if (n >= Nn) return;
    const int c = cnt[n];
    const int inb = c < CAP ? c : CAP;
    const int* bk = bucket + (long)n * CAP;
    float a0 = 0.f, a1 = 0.f;
    int e = 0;
    for (; e + 3 < inb; e += 4) {
        int s0 = bk[e], s1 = bk[e + 1], s2 = bk[e + 2], s3 = bk[e + 3];
        us2 v0 = *(const us2*)(P2 + (long)s0 * 128 + l * 2);
        us2 v1 = *(const us2*)(P2 + (long)s1 * 128 + l * 2);
        us2 v2 = *(const us2*)(P2 + (long)s2 * 128 + l * 2);
        us2 v3 = *(const us2*)(P2 + (long)s3 * 128 + l * 2);
        a0 += (b2f(v0[0]) + b2f(v1[0])) + (b2f(v2[0]) + b2f(v3[0]));
        a1 += (b2f(v0[1]) + b2f(v1[1])) + (b2f(v2[1]) + b2f(v3[1]));
    }
    for (; e < inb; ++e) {
        int s0 = bk[e];
        us2 v0 = *(const us2*)(P2 + (long)s0 * 128 + l * 2);
        a0 += b2f(v0[0]); a1 += b2f(v0[1]);
    }
    const int ns = *nspill;
    if (ns > 0) {
        int lim = ns < SPILLMAX ? ns : SPILLMAX;
        for (int q = 0; q < lim; ++q) {
            if (spill[2 * q] == n) {
                int s0 = spill[2 * q + 1];
                us2 v0 = *(const us2*)(P2 + (long)s0 * 128 + l * 2);
                a0 += b2f(v0[0]); a1 += b2f(v0[1]);
            }
        }
    }
    float inv = 1.0f / (float)(c > 1 ? c : 1);
    us2 sf = *(const us2*)(C2s + (long)n * 128 + l * 2);
    us2 bv = *(const us2*)(b2c + l * 2);
    float o0 = b2f(sf[0]) + a0 * inv + b2f(bv[0]);
    float o1 = b2f(sf[1]) + a1 * inv + b2f(bv[1]);
    if (flags[0]) {
        float* o = (float*)outv + (long)n * 128 + l * 2;
        o[0] = o0; o[1] = o1;
    } else {
        us2 ob; ob[0] = f2b(o0); ob[1] = f2b(o1);
        *(us2*)((u16*)outv + (long)n * 128 + l * 2) = ob;
    }
}

// ================= launch ========================================================
extern "C" void kernel_launch(void* const* d_in, const int* in_sizes, int n_in,
                              void* d_out, int out_size, void* d_ws, size_t ws_size,
                              hipStream_t stream) {
    const int D = 512, NCLS = 128;
    const int Nn = in_sizes[0] / D;            // 10000
    const int E  = in_sizes[5];                // 160000
    const int mtiles = (Nn + 127) / 128;       // 79
    const int mt64 = (Nn + 63) / 64;           // 157
    const int Mpad = mtiles * 128;             // 10112
    const int nFill = (E + 255) / 256;         // 625
    const int nHb = (Nn * D / 8 + 255) / 256;  // 2500

    const int* src = (const int*)d_in[5];
    const int* dst = (const int*)d_in[6];

    char* p = (char*)d_ws;
    u16* Hb  = (u16*)p; p += (size_t)Mpad * D * 2;
    u16* h1  = (u16*)p; p += (size_t)Mpad * D * 2;
    u16* C1s = (u16*)p; p += (size_t)Mpad * D * 2;
    u8*  P1  = (u8*)p;  p += (size_t)Mpad * D;        // fp8 e4m3
    u16* C2s = (u16*)p; p += (size_t)Mpad * NCLS * 2;
    u16* P2  = (u16*)p; p += (size_t)Mpad * NCLS * 2;
    u16* W1T = (u16*)p; p += (size_t)1024 * D * 2;
    u16* W2T = (u16*)p; p += (size_t)256 * D * 2;
    u16* b1c = (u16*)p; p += 1024;
    u16* b2c = (u16*)p; p += 1024;
    int* flags  = (int*)p; p += 256;
    int* cnt    = (int*)p; p += (size_t)(Nn + 60) * 4;
    int* nspill = cnt + Nn;
    int* bucket = (int*)p; p += (size_t)Nn * CAP * 4;
    int* spill  = (int*)p; p += (size_t)SPILLMAX * 2 * 4;

    hipMemsetAsync(cnt, 0, (size_t)(Nn + 60) * 4, stream);

    // D1: buckets + all conversions
    k_d1<<<nFill + nHb + 641, 256, 0, stream>>>(
        src, dst, E, Nn, cnt, bucket, nspill, spill,
        d_in[0], d_in[1], d_in[2], d_in[3], d_in[4],
        Hb, W1T, W2T, b1c, b2c, flags, nFill, nHb);

    // D2: [C1s(bf16) | P1(fp8)] = Hb @ W1T^T  [64x128 tiles, BK=64, 1256 blocks]
    k_gemm1_64<<<dim3(mt64, 8), 256, 0, stream>>>(Hb, W1T, C1s, P1, Nn);

    // D3: h1 = relu(C1s + mean(P1[nbrs]) + b1)  [wave-per-node]
    agg_h1<<<(Nn + 3) / 4, 256, 0, stream>>>(P1, C1s, b1c, cnt, bucket,
                                             nspill, spill, h1, Nn);

    // D4: [C2s|P2] = h1 @ W2T^T  [64x128 tiles, BK=64, 314 blocks]
    k_gemm2_64<<<dim3(mt64, 2), 256, 0, stream>>>(h1, W2T, C2s, P2, Nn);

    // D5: out = C2s + mean(P2[nbrs]) + b2
    agg_out<<<(Nn + 3) / 4, 256, 0, stream>>>(P2, C2s, b2c, cnt, bucket,
                                              nspill, spill, d_out, Nn, flags);
}